// Round 5
// baseline (891.904 us; speedup 1.0000x reference)
//
#include <hip/hip_runtime.h>
#include <hip/hip_bf16.h>

typedef float f32x4 __attribute__((ext_vector_type(4)));
typedef __bf16 bf16x8 __attribute__((ext_vector_type(8)));
typedef unsigned short u16x4 __attribute__((ext_vector_type(4)));
typedef unsigned int u32;
typedef unsigned int u32x4 __attribute__((ext_vector_type(4)));

#if defined(__has_builtin)
#if __has_builtin(__builtin_amdgcn_exp2f)
#define EXP2F(x) __builtin_amdgcn_exp2f(x)
#else
#define EXP2F(x) exp2f(x)
#endif
#if __has_builtin(__builtin_amdgcn_rcpf)
#define RCPF(x) __builtin_amdgcn_rcpf(x)
#else
#define RCPF(x) (1.0f/(x))
#endif
#else
#define EXP2F(x) exp2f(x)
#define RCPF(x) (1.0f/(x))
#endif

#define MFMA16(a,b,c) __builtin_amdgcn_mfma_f32_16x16x32_bf16((a),(b),(c),0,0,0)

__device__ __forceinline__ unsigned short f2bf(float f) {
  return __builtin_bit_cast(unsigned short, (__bf16)f);
}

// pack two f32 -> one u32 of 2 bf16 (RNE), lo = a, hi = b
__device__ __forceinline__ u32 pkbf(float a, float b) {
  u32 d;
  asm("v_cvt_pk_bf16_f32 %0, %1, %2" : "=v"(d) : "v"(a), "v"(b));
  return d;
}

// Build permuted W1^T in d_ws: W1Tg[rho][iota], bf16.
//   rho: jb=rho>>5, jf=(rho>>4)&1, a=(rho>>2)&3, c=rho&3  -> j = jb*32 + a*8 + jf*4 + c   [pi]
//   iota: kb=io>>5,  u=(io>>3)&3,  v=io&7                 -> i = kb*32 + (v>>2)*16 + u*4 + (v&3)  [sigma]
__global__ __launch_bounds__(256) void hn_prep(const float* __restrict__ W1,
                                               unsigned short* __restrict__ W1T) {
  int t = blockIdx.x * 256 + threadIdx.x;  // t = rho*128 + iota
  int rho = t >> 7, io = t & 127;
  int j = (rho >> 5) * 32 + ((rho >> 2) & 3) * 8 + ((rho >> 4) & 1) * 4 + (rho & 3);
  int i = (io >> 5) * 32 + ((io & 7) >> 2) * 16 + ((io >> 3) & 3) * 4 + (io & 7 & 3);
  W1T[t] = f2bf(W1[i * 512 + j]);
}

// One block = 128 batch rows (8 waves x 16 rows), 512 blocks.
// Per step: phase F (all 16 jblk fwd, s -> 64 regs), then phase B (all bwd).
// Serial fwd->act->bwd chain happens once per STEP, not per jblk -> deep ILP.
__global__ __launch_bounds__(512, 2) void hn_main(
    const float* __restrict__ x, const float* __restrict__ W1,
    const float* __restrict__ b1, const float* __restrict__ W2,
    const unsigned short* __restrict__ W1T, float* __restrict__ out) {
  __shared__ __align__(16) char w1l[131072];  // W1 bf16 [128 i][512 j] natural, ^((i&7)<<4)
  __shared__ __align__(16) float b1s[512];    // b1 * 2*log2(e)
  __shared__ __align__(16) float w2s[512];

  const int tid = threadIdx.x;
  const int lane = tid & 63;
  const int w = tid >> 6;      // 0..7
  const int m = lane & 15;
  const int g = lane >> 4;

  // ---- stage natural W1 -> LDS (bwd A-frags: j-contiguous 16B runs)
  for (int it = tid; it < 16384; it += 512) {
    int flat = it << 2;            // element index = i*512 + j
    int i = flat >> 9;
    f32x4 v = *(const f32x4*)(W1 + flat);
    u16x4 pk;
#pragma unroll
    for (int c = 0; c < 4; ++c) pk[c] = f2bf(v[c]);
    int ba = flat << 1;
    *(u16x4*)(w1l + (ba ^ ((i & 7) << 4))) = pk;
  }
  if (tid < 512) {
    b1s[tid] = b1[tid] * 2.8853900817779268f;
    w2s[tid] = W2[tid];
  }
  __syncthreads();

  const int b0 = blockIdx.x * 128 + w * 16;
  const float* xrow = x + (long)(b0 + m) * 256;

  // q/p in sigma layout: q[kb][r] = (row b0+m, i = 32kb + 16*(r>>2) + 4g + (r&3))
  float q[4][8], p[4][8];
#pragma unroll
  for (int kb = 0; kb < 4; ++kb) {
    const float* r0 = xrow + kb * 32 + g * 4;
#pragma unroll
    for (int h = 0; h < 2; ++h) {
      f32x4 qv = *(const f32x4*)(r0 + h * 16);
      f32x4 pv = *(const f32x4*)(r0 + h * 16 + 128);
#pragma unroll
      for (int rr = 0; rr < 4; ++rr) {
        q[kb][4 * h + rr] = qv[rr];
        p[kb][4 * h + rr] = pv[rr];
      }
    }
  }

  // lane-constant bases
  const char* aptr = (const char*)W1T + m * 256 + g * 16;  // fwd A: row rho=..+m, iota-chunk
  const int s45 = (m & 3) << 4, s6 = (m & 4) << 4;
  const int ybase = ((m * 1024 + g * 16) ^ s45);            // bwd A from LDS

#pragma unroll 1
  for (int step = 0; step < 10; ++step) {
    // ---- qb: bf16 image of q, once per step (16 regs)
    u32x4 qbw[4];
#pragma unroll
    for (int kb = 0; kb < 4; ++kb)
#pragma unroll
      for (int h = 0; h < 4; ++h)
        qbw[kb][h] = pkbf(q[kb][2 * h], q[kb][2 * h + 1]);

    // ---- PHASE F: all fwd tiles; s staged in 64 regs (static indices, full unroll)
    u32x4 S[16];
#pragma unroll
    for (int jblk = 0; jblk < 16; ++jblk) {
      f32x4 z0 = f32x4{0.f, 0.f, 0.f, 0.f};
      f32x4 z1 = f32x4{0.f, 0.f, 0.f, 0.f};
#pragma unroll
      for (int kb = 0; kb < 4; ++kb) {
        bf16x8 qb = __builtin_bit_cast(bf16x8, qbw[kb]);
        bf16x8 a0 = *(const bf16x8*)(aptr + jblk * 8192 + kb * 64);
        bf16x8 a1 = *(const bf16x8*)(aptr + jblk * 8192 + 4096 + kb * 64);
        z0 = MFMA16(a0, qb, z0);
        z1 = MFMA16(a1, qb, z1);
      }
      // act: s = W2[j] * sech^2(z + b1[j]);  C-row (jf,rr) <-> j = 32jblk+8g+4jf+rr
      u32x4 sp;
#pragma unroll
      for (int jf = 0; jf < 2; ++jf) {
        f32x4 b1v = *(const f32x4*)(b1s + jblk * 32 + g * 8 + jf * 4);
        f32x4 w2v = *(const f32x4*)(w2s + jblk * 32 + g * 8 + jf * 4);
        const f32x4 zv = jf ? z1 : z0;
        float sv[4];
#pragma unroll
        for (int rr = 0; rr < 4; ++rr) {
          float zz = fmaf(zv[rr], 2.8853900817779268f, b1v[rr]);
          float e = EXP2F(zz);                 // e^(2(z+b1))
          float u = RCPF(e + 1.f);
          float th = fmaf(-2.f, u, 1.f);       // tanh
          sv[rr] = fmaf(-th * th, w2v[rr], w2v[rr]);
        }
        sp[jf * 2 + 0] = pkbf(sv[0], sv[1]);
        sp[jf * 2 + 1] = pkbf(sv[2], sv[3]);
      }
      S[jblk] = sp;
    }

    // ---- PHASE B: all bwd tiles; 8 independent gacc chains, LDS-fed
    f32x4 gacc[8];  // C: col b = m, row i = 16nf + 4g + rr
#pragma unroll
    for (int nf = 0; nf < 8; ++nf) gacc[nf] = f32x4{0.f, 0.f, 0.f, 0.f};
#pragma unroll
    for (int jblk = 0; jblk < 16; ++jblk) {
      bf16x8 sB = __builtin_bit_cast(bf16x8, S[jblk]);
      const int joff = (jblk * 64) ^ s6;
#pragma unroll
      for (int nf = 0; nf < 8; ++nf) {
        bf16x8 af = *(const bf16x8*)(w1l + ybase + nf * 16384 + joff);
        gacc[nf] = MFMA16(af, sB, gacc[nf]);
      }
    }

    // q += dt * p_old  (gacc was computed from old q)
#pragma unroll
    for (int kb = 0; kb < 4; ++kb)
#pragma unroll
      for (int r = 0; r < 8; ++r)
        q[kb][r] = fmaf(0.1f, p[kb][r], q[kb][r]);

    // p -= dt * g : gacc C-layout == p sigma-frag layout, pure f32, static indices
#pragma unroll
    for (int kb = 0; kb < 4; ++kb)
#pragma unroll
      for (int r = 0; r < 8; ++r)
        p[kb][r] = fmaf(-0.1f, gacc[2 * kb + (r >> 2)][r & 3], p[kb][r]);
  }

  // ---- store concat(q, p) with the same sigma addressing
  float* orow = out + (long)(b0 + m) * 256;
#pragma unroll
  for (int kb = 0; kb < 4; ++kb) {
    float* o = orow + kb * 32 + g * 4;
#pragma unroll
    for (int h = 0; h < 2; ++h) {
      f32x4 qv, pv;
#pragma unroll
      for (int rr = 0; rr < 4; ++rr) {
        qv[rr] = q[kb][4 * h + rr];
        pv[rr] = p[kb][4 * h + rr];
      }
      *(f32x4*)(o + h * 16) = qv;
      *(f32x4*)(o + h * 16 + 128) = pv;
    }
  }
}

extern "C" void kernel_launch(void* const* d_in, const int* in_sizes, int n_in,
                              void* d_out, int out_size, void* d_ws, size_t ws_size,
                              hipStream_t stream) {
  const float* x  = (const float*)d_in[0];
  const float* W1 = (const float*)d_in[1];
  const float* b1 = (const float*)d_in[2];
  const float* W2 = (const float*)d_in[3];
  // d_in[4] = b2: affects only V's value, not its gradient -> unused.
  float* out = (float*)d_out;
  unsigned short* w1t = (unsigned short*)d_ws;  // 128 KB bf16 permuted W1^T

  hipLaunchKernelGGL(hn_prep, dim3(256), dim3(256), 0, stream, W1, w1t);
  hipLaunchKernelGGL(hn_main, dim3(512), dim3(512), 0, stream,
                     x, W1, b1, W2, w1t, out);
}

// Round 6
// 610.645 us; speedup vs baseline: 1.4606x; 1.4606x over previous
//
#include <hip/hip_runtime.h>
#include <hip/hip_bf16.h>

typedef float f32x4 __attribute__((ext_vector_type(4)));
typedef __bf16 bf16x8 __attribute__((ext_vector_type(8)));
typedef unsigned short u16x4 __attribute__((ext_vector_type(4)));
typedef unsigned int u32;
typedef unsigned int u32x4 __attribute__((ext_vector_type(4)));

#if defined(__has_builtin)
#if __has_builtin(__builtin_amdgcn_exp2f)
#define EXP2F(x) __builtin_amdgcn_exp2f(x)
#else
#define EXP2F(x) exp2f(x)
#endif
#if __has_builtin(__builtin_amdgcn_rcpf)
#define RCPF(x) __builtin_amdgcn_rcpf(x)
#else
#define RCPF(x) (1.0f/(x))
#endif
#else
#define EXP2F(x) exp2f(x)
#define RCPF(x) (1.0f/(x))
#endif

#define MFMA16(a,b,c) __builtin_amdgcn_mfma_f32_16x16x32_bf16((a),(b),(c),0,0,0)

__device__ __forceinline__ unsigned short f2bf(float f) {
  return __builtin_bit_cast(unsigned short, (__bf16)f);
}

// pack two f32 -> one u32 of 2 bf16 (RNE), lo = a, hi = b
__device__ __forceinline__ u32 pkbf(float a, float b) {
  u32 d;
  asm("v_cvt_pk_bf16_f32 %0, %1, %2" : "=v"(d) : "v"(a), "v"(b));
  return d;
}

// Build permuted W1^T in d_ws: W1Tg[rho][iota], bf16.
//   rho: jb=rho>>5, jf=(rho>>4)&1, a=(rho>>2)&3, c=rho&3  -> j = jb*32 + a*8 + jf*4 + c   [pi]
//   iota: kb=io>>5,  u=(io>>3)&3,  v=io&7                 -> i = kb*32 + (v>>2)*16 + u*4 + (v&3)  [sigma]
__global__ __launch_bounds__(256) void hn_prep(const float* __restrict__ W1,
                                               unsigned short* __restrict__ W1T) {
  int t = blockIdx.x * 256 + threadIdx.x;  // t = rho*128 + iota
  int rho = t >> 7, io = t & 127;
  int j = (rho >> 5) * 32 + ((rho >> 2) & 3) * 8 + ((rho >> 4) & 1) * 4 + (rho & 3);
  int i = (io >> 5) * 32 + ((io & 7) >> 2) * 16 + ((io >> 3) & 3) * 4 + (io & 7 & 3);
  W1T[t] = f2bf(W1[i * 512 + j]);
}

// One block = 256 batch rows (16 waves x 16 rows), 256 blocks -> all-resident,
// 4 waves/SIMD (cap 128 regs). Persistent state only q32+p32+qbw16 = 80 regs:
// backward partials fold into p per-jblk (sigma alignment), no gacc array.
__global__ __launch_bounds__(1024, 4) void hn_main(
    const float* __restrict__ x, const float* __restrict__ W1,
    const float* __restrict__ b1, const float* __restrict__ W2,
    const unsigned short* __restrict__ W1T, float* __restrict__ out) {
  __shared__ __align__(16) char w1l[131072];  // W1 bf16 [128 i][512 j] natural, ^((i&7)<<4)
  __shared__ __align__(16) float b1s[512];    // b1 * 2*log2(e)
  __shared__ __align__(16) float w2s[512];

  const int tid = threadIdx.x;
  const int lane = tid & 63;
  const int w = tid >> 6;      // 0..15
  const int m = lane & 15;
  const int g = lane >> 4;

  // ---- stage natural W1 -> LDS (bwd A-frags: j-contiguous 16B runs)
  for (int it = tid; it < 16384; it += 1024) {
    int flat = it << 2;            // element index = i*512 + j
    int i = flat >> 9;
    f32x4 v = *(const f32x4*)(W1 + flat);
    u16x4 pk;
#pragma unroll
    for (int c = 0; c < 4; ++c) pk[c] = f2bf(v[c]);
    int ba = flat << 1;
    *(u16x4*)(w1l + (ba ^ ((i & 7) << 4))) = pk;
  }
  if (tid < 512) {
    b1s[tid] = b1[tid] * 2.8853900817779268f;
    w2s[tid] = W2[tid];
  }
  __syncthreads();

  const int b0 = blockIdx.x * 256 + w * 16;
  const float* xrow = x + (long)(b0 + m) * 256;

  // q/p in sigma layout: q[kb][r] = (row b0+m, i = 32kb + 16*(r>>2) + 4g + (r&3))
  float q[4][8], p[4][8];
#pragma unroll
  for (int kb = 0; kb < 4; ++kb) {
    const float* r0 = xrow + kb * 32 + g * 4;
#pragma unroll
    for (int h = 0; h < 2; ++h) {
      f32x4 qv = *(const f32x4*)(r0 + h * 16);
      f32x4 pv = *(const f32x4*)(r0 + h * 16 + 128);
#pragma unroll
      for (int rr = 0; rr < 4; ++rr) {
        q[kb][4 * h + rr] = qv[rr];
        p[kb][4 * h + rr] = pv[rr];
      }
    }
  }

  // lane-constant bases
  const char* aptr = (const char*)W1T + m * 256 + g * 16;  // fwd A: row rho=..+m, iota-chunk
  const int s45 = (m & 3) << 4, s6 = (m & 4) << 4;
  const int ybase = ((m * 1024 + g * 16) ^ s45);            // bwd A from LDS

#pragma unroll 1
  for (int step = 0; step < 10; ++step) {
    // ---- snapshot q_old as bf16 (16 regs), then advance q with p_old
    u32x4 qbw[4];
#pragma unroll
    for (int kb = 0; kb < 4; ++kb)
#pragma unroll
      for (int h = 0; h < 4; ++h)
        qbw[kb][h] = pkbf(q[kb][2 * h], q[kb][2 * h + 1]);

#pragma unroll
    for (int kb = 0; kb < 4; ++kb)
#pragma unroll
      for (int r = 0; r < 8; ++r)
        q[kb][r] = fmaf(0.1f, p[kb][r], q[kb][r]);

    // ---- per jblk: fwd (q_old) -> act -> fold bwd partial straight into p
#pragma unroll 1
    for (int jblk = 0; jblk < 16; ++jblk) {
      f32x4 z0 = f32x4{0.f, 0.f, 0.f, 0.f};
      f32x4 z1 = f32x4{0.f, 0.f, 0.f, 0.f};
#pragma unroll
      for (int kb = 0; kb < 4; ++kb) {
        bf16x8 qb = __builtin_bit_cast(bf16x8, qbw[kb]);
        bf16x8 a0 = *(const bf16x8*)(aptr + jblk * 8192 + kb * 64);
        bf16x8 a1 = *(const bf16x8*)(aptr + jblk * 8192 + 4096 + kb * 64);
        z0 = MFMA16(a0, qb, z0);
        z1 = MFMA16(a1, qb, z1);
      }
      // act: s = W2[j] * sech^2(z + b1[j]);  C-row (jf,rr) <-> j = 32jblk+8g+4jf+rr
      u32x4 sp;
#pragma unroll
      for (int jf = 0; jf < 2; ++jf) {
        f32x4 b1v = *(const f32x4*)(b1s + jblk * 32 + g * 8 + jf * 4);
        f32x4 w2v = *(const f32x4*)(w2s + jblk * 32 + g * 8 + jf * 4);
        const f32x4 zv = jf ? z1 : z0;
        float sv[4];
#pragma unroll
        for (int rr = 0; rr < 4; ++rr) {
          float zz = fmaf(zv[rr], 2.8853900817779268f, b1v[rr]);
          float e = EXP2F(zz);                 // e^(2(z+b1))
          float u = RCPF(e + 1.f);
          float th = fmaf(-2.f, u, 1.f);       // tanh
          sv[rr] = fmaf(-th * th, w2v[rr], w2v[rr]);
        }
        sp[jf * 2 + 0] = pkbf(sv[0], sv[1]);
        sp[jf * 2 + 1] = pkbf(sv[2], sv[3]);
      }
      bf16x8 sB = __builtin_bit_cast(bf16x8, sp);
      // bwd: partial g for this jblk, folded into p immediately.
      // gtile[nf] C-layout row i=16nf+4g+rr, col b=m  ==  p[nf>>1][(nf&1)*4+rr]
      const int joff = (jblk * 64) ^ s6;
      const f32x4 zc = f32x4{0.f, 0.f, 0.f, 0.f};
#pragma unroll
      for (int nf = 0; nf < 8; ++nf) {
        bf16x8 af = *(const bf16x8*)(w1l + ybase + nf * 16384 + joff);
        f32x4 gt = MFMA16(af, sB, zc);
        const int kb = nf >> 1, h4 = (nf & 1) * 4;
#pragma unroll
        for (int rr = 0; rr < 4; ++rr)
          p[kb][h4 + rr] = fmaf(-0.1f, gt[rr], p[kb][h4 + rr]);
      }
    }
    __syncthreads();  // phase-lock waves (L1 locality on W1Tg slices)
  }

  // ---- store concat(q, p) with the same sigma addressing
  float* orow = out + (long)(b0 + m) * 256;
#pragma unroll
  for (int kb = 0; kb < 4; ++kb) {
    float* o = orow + kb * 32 + g * 4;
#pragma unroll
    for (int h = 0; h < 2; ++h) {
      f32x4 qv, pv;
#pragma unroll
      for (int rr = 0; rr < 4; ++rr) {
        qv[rr] = q[kb][4 * h + rr];
        pv[rr] = p[kb][4 * h + rr];
      }
      *(f32x4*)(o + h * 16) = qv;
      *(f32x4*)(o + h * 16 + 128) = pv;
    }
  }
}

extern "C" void kernel_launch(void* const* d_in, const int* in_sizes, int n_in,
                              void* d_out, int out_size, void* d_ws, size_t ws_size,
                              hipStream_t stream) {
  const float* x  = (const float*)d_in[0];
  const float* W1 = (const float*)d_in[1];
  const float* b1 = (const float*)d_in[2];
  const float* W2 = (const float*)d_in[3];
  // d_in[4] = b2: affects only V's value, not its gradient -> unused.
  float* out = (float*)d_out;
  unsigned short* w1t = (unsigned short*)d_ws;  // 128 KB bf16 permuted W1^T

  hipLaunchKernelGGL(hn_prep, dim3(256), dim3(256), 0, stream, W1, w1t);
  hipLaunchKernelGGL(hn_main, dim3(256), dim3(1024), 0, stream,
                     x, W1, b1, W2, w1t, out);
}

// Round 8
// 351.442 us; speedup vs baseline: 2.5378x; 1.7375x over previous
//
#include <hip/hip_runtime.h>
#include <hip/hip_bf16.h>

typedef float f32x4 __attribute__((ext_vector_type(4)));
typedef __bf16 bf16x8 __attribute__((ext_vector_type(8)));
typedef unsigned int u32;
typedef unsigned int u32x4 __attribute__((ext_vector_type(4)));

#if defined(__has_builtin)
#if __has_builtin(__builtin_amdgcn_exp2f)
#define EXP2F(x) __builtin_amdgcn_exp2f(x)
#else
#define EXP2F(x) exp2f(x)
#endif
#if __has_builtin(__builtin_amdgcn_rcpf)
#define RCPF(x) __builtin_amdgcn_rcpf(x)
#else
#define RCPF(x) (1.0f/(x))
#endif
#else
#define EXP2F(x) exp2f(x)
#define RCPF(x) (1.0f/(x))
#endif

#define MFMA16(a,b,c) __builtin_amdgcn_mfma_f32_16x16x32_bf16((a),(b),(c),0,0,0)

__device__ __forceinline__ unsigned short f2bf(float f) {
  return __builtin_bit_cast(unsigned short, (__bf16)f);
}

// pack two f32 -> one u32 of 2 bf16 (RNE), lo = a, hi = b
__device__ __forceinline__ u32 pkbf(float a, float b) {
  u32 d;
  asm("v_cvt_pk_bf16_f32 %0, %1, %2" : "=v"(d) : "v"(a), "v"(b));
  return d;
}

// d_ws layout: [0..65535] = W1Tg (pi x sigma permuted W1^T, fwd A image)
//              [65536..131071] = W1b (natural bf16 W1, bwd A image)
//   rho: jb=rho>>5, jf=(rho>>4)&1, a=(rho>>2)&3, c=rho&3  -> j = jb*32 + a*8 + jf*4 + c   [pi]
//   iota: kb=io>>5,  u=(io>>3)&3,  v=io&7                 -> i = kb*32 + (v>>2)*16 + u*4 + (v&3)  [sigma]
__global__ __launch_bounds__(256) void hn_prep(const float* __restrict__ W1,
                                               unsigned short* __restrict__ ws) {
  int t = blockIdx.x * 256 + threadIdx.x;  // 65536 threads
  int rho = t >> 7, io = t & 127;
  int j = (rho >> 5) * 32 + ((rho >> 2) & 3) * 8 + ((rho >> 4) & 1) * 4 + (rho & 3);
  int i = (io >> 5) * 32 + ((io >> 2) & 1) * 16 + ((io >> 3) & 3) * 4 + (io & 3);
  ws[t] = f2bf(W1[i * 512 + j]);          // W1Tg[rho][io]
  ws[65536 + t] = f2bf(W1[t]);            // W1b natural [i][j]
}

// One block = 256 batch rows (8 waves x 32 rows), 256 blocks, 2 waves/SIMD.
// fwd A from LDS (low latency, head of chain); bwd A from global/L2
// (latency-tolerant: 16 independent gacc chains, data-independent addresses).
__global__ __launch_bounds__(512, 2) void hn_main(
    const float* __restrict__ x, const float* __restrict__ W1,
    const float* __restrict__ b1, const float* __restrict__ W2,
    const unsigned short* __restrict__ wsp, float* __restrict__ out) {
  __shared__ __align__(16) char w1f[131072];  // W1Tg bf16 [512 rho][128 io], ^((rho&7)<<4)
  __shared__ __align__(16) float b1s[512];    // b1 * 2*log2(e)
  __shared__ __align__(16) float w2s[512];

  const int tid = threadIdx.x;
  const int lane = tid & 63;
  const int w = tid >> 6;      // 0..7
  const int m = lane & 15;
  const int g = lane >> 4;

  // ---- stage W1Tg -> LDS (linear copy + row-XOR swizzle; XOR only, no carries)
  for (int it = tid; it < 8192; it += 512) {
    int flat = it << 3;                      // element index = rho*128 + io, 8 at a time
    int rho = flat >> 7;
    u32x4 v = *(const u32x4*)(wsp + flat);   // 16B = 8 bf16
    int ba = flat << 1;
    *(u32x4*)(w1f + (ba ^ ((rho & 7) << 4))) = v;
  }
  if (tid < 512) {
    b1s[tid] = b1[tid] * 2.8853900817779268f;
    w2s[tid] = W2[tid];
  }
  __syncthreads();

  const int b0 = blockIdx.x * 256 + w * 32;

  // q/p in sigma layout: q[bf][kb][r] = (row b0+16bf+m, i = 32kb + 16*(r>>2) + 4g + (r&3))
  float q[2][4][8], p[2][4][8];
#pragma unroll
  for (int bf = 0; bf < 2; ++bf)
#pragma unroll
    for (int kb = 0; kb < 4; ++kb) {
      const float* r0 = x + (long)(b0 + 16 * bf + m) * 256 + kb * 32 + g * 4;
#pragma unroll
      for (int h = 0; h < 2; ++h) {
        f32x4 qv = *(const f32x4*)(r0 + h * 16);
        f32x4 pv = *(const f32x4*)(r0 + h * 16 + 128);
#pragma unroll
        for (int rr = 0; rr < 4; ++rr) {
          q[bf][kb][4 * h + rr] = qv[rr];
          p[bf][kb][4 * h + rr] = pv[rr];
        }
      }
    }

  // lane-constant bases. CRITICAL: swizzle XOR applied to the FULL low-bit
  // address (m*256 + kb*64 + g*16) so no later add overlaps XORed bits 4-6.
  const int sw = (m & 7) << 4;
  const int lbF[4] = {
      (m * 256 + 0 * 64 + g * 16) ^ sw,
      (m * 256 + 1 * 64 + g * 16) ^ sw,
      (m * 256 + 2 * 64 + g * 16) ^ sw,
      (m * 256 + 3 * 64 + g * 16) ^ sw};
  const unsigned short* W1b = wsp + 65536;
  const char* bptr = (const char*)W1b + m * 1024 + g * 16;      // bwd A row m+16nf, j-chunk

#pragma unroll 1
  for (int step = 0; step < 10; ++step) {
    // bf16 snapshot of q (once per step)
    u32x4 qbw[2][4];
#pragma unroll
    for (int bf = 0; bf < 2; ++bf)
#pragma unroll
      for (int kb = 0; kb < 4; ++kb)
#pragma unroll
        for (int h = 0; h < 4; ++h)
          qbw[bf][kb][h] = pkbf(q[bf][kb][2 * h], q[bf][kb][2 * h + 1]);

    f32x4 gacc[2][8];  // C: col b = m+16bf, row i = 16nf + 4g + rr
#pragma unroll
    for (int bf = 0; bf < 2; ++bf)
#pragma unroll
      for (int nf = 0; nf < 8; ++nf) gacc[bf][nf] = f32x4{0.f, 0.f, 0.f, 0.f};

#pragma unroll 2
    for (int jblk = 0; jblk < 16; ++jblk) {
      // ---- forward: z tile from LDS A + q regs
      f32x4 z[2][2];
      z[0][0] = f32x4{0.f,0.f,0.f,0.f}; z[0][1] = f32x4{0.f,0.f,0.f,0.f};
      z[1][0] = f32x4{0.f,0.f,0.f,0.f}; z[1][1] = f32x4{0.f,0.f,0.f,0.f};
#pragma unroll
      for (int kb = 0; kb < 4; ++kb) {
        bf16x8 qb0 = __builtin_bit_cast(bf16x8, qbw[0][kb]);
        bf16x8 qb1 = __builtin_bit_cast(bf16x8, qbw[1][kb]);
        bf16x8 a0 = *(const bf16x8*)(w1f + lbF[kb] + jblk * 8192);
        bf16x8 a1 = *(const bf16x8*)(w1f + lbF[kb] + jblk * 8192 + 4096);
        z[0][0] = MFMA16(a0, qb0, z[0][0]);
        z[0][1] = MFMA16(a0, qb1, z[0][1]);
        z[1][0] = MFMA16(a1, qb0, z[1][0]);
        z[1][1] = MFMA16(a1, qb1, z[1][1]);
      }
      // ---- act: s = W2[j] * sech^2(z + b1[j]); C-row (jf,rr) <-> j = 32jblk+8g+4jf+rr
      u32x4 sp0, sp1;
#pragma unroll
      for (int jf = 0; jf < 2; ++jf) {
        f32x4 b1v = *(const f32x4*)(b1s + jblk * 32 + g * 8 + jf * 4);
        f32x4 w2v = *(const f32x4*)(w2s + jblk * 32 + g * 8 + jf * 4);
#pragma unroll
        for (int bf = 0; bf < 2; ++bf) {
          const f32x4 zv = z[jf][bf];
          float sv[4];
#pragma unroll
          for (int rr = 0; rr < 4; ++rr) {
            float zz = fmaf(zv[rr], 2.8853900817779268f, b1v[rr]);
            float e = EXP2F(zz);                 // e^(2(z+b1))
            float u = RCPF(e + 1.f);
            float th = fmaf(-2.f, u, 1.f);       // tanh
            sv[rr] = fmaf(-th * th, w2v[rr], w2v[rr]);
          }
          u32 w0 = pkbf(sv[0], sv[1]);
          u32 w1p = pkbf(sv[2], sv[3]);
          if (bf == 0) { sp0[jf * 2] = w0; sp0[jf * 2 + 1] = w1p; }
          else         { sp1[jf * 2] = w0; sp1[jf * 2 + 1] = w1p; }
        }
      }
      bf16x8 sB0 = __builtin_bit_cast(bf16x8, sp0);
      bf16x8 sB1 = __builtin_bit_cast(bf16x8, sp1);
      // ---- backward: gacc += W1b(A, global/L2) * s^T(B); addresses data-independent
#pragma unroll
      for (int nf = 0; nf < 8; ++nf) {
        bf16x8 af = *(const bf16x8*)(bptr + nf * 16384 + jblk * 64);
        gacc[0][nf] = MFMA16(af, sB0, gacc[0][nf]);
        gacc[1][nf] = MFMA16(af, sB1, gacc[1][nf]);
      }
    }

    // q += dt * p_old  (gacc was computed from old q)
#pragma unroll
    for (int bf = 0; bf < 2; ++bf)
#pragma unroll
      for (int kb = 0; kb < 4; ++kb)
#pragma unroll
        for (int r = 0; r < 8; ++r)
          q[bf][kb][r] = fmaf(0.1f, p[bf][kb][r], q[bf][kb][r]);

    // p -= dt * g : gacc C-layout == p sigma-frag layout, static indices
#pragma unroll
    for (int bf = 0; bf < 2; ++bf)
#pragma unroll
      for (int kb = 0; kb < 4; ++kb)
#pragma unroll
        for (int r = 0; r < 8; ++r)
          p[bf][kb][r] = fmaf(-0.1f, gacc[bf][2 * kb + (r >> 2)][r & 3], p[bf][kb][r]);
  }

  // ---- store concat(q, p) with the same sigma addressing
#pragma unroll
  for (int bf = 0; bf < 2; ++bf)
#pragma unroll
    for (int kb = 0; kb < 4; ++kb) {
      float* o = out + (long)(b0 + 16 * bf + m) * 256 + kb * 32 + g * 4;
#pragma unroll
      for (int h = 0; h < 2; ++h) {
        f32x4 qv, pv;
#pragma unroll
        for (int rr = 0; rr < 4; ++rr) {
          qv[rr] = q[bf][kb][4 * h + rr];
          pv[rr] = p[bf][kb][4 * h + rr];
        }
        *(f32x4*)(o + h * 16) = qv;
        *(f32x4*)(o + h * 16 + 128) = pv;
      }
    }
}

extern "C" void kernel_launch(void* const* d_in, const int* in_sizes, int n_in,
                              void* d_out, int out_size, void* d_ws, size_t ws_size,
                              hipStream_t stream) {
  const float* x  = (const float*)d_in[0];
  const float* W1 = (const float*)d_in[1];
  const float* b1 = (const float*)d_in[2];
  const float* W2 = (const float*)d_in[3];
  // d_in[4] = b2: affects only V's value, not its gradient -> unused.
  float* out = (float*)d_out;
  unsigned short* wsp = (unsigned short*)d_ws;  // 256 KB: W1Tg + W1b

  hipLaunchKernelGGL(hn_prep, dim3(256), dim3(256), 0, stream, W1, wsp);
  hipLaunchKernelGGL(hn_main, dim3(256), dim3(512), 0, stream,
                     x, W1, b1, W2, wsp, out);
}